// Round 1
// baseline (968.931 us; speedup 1.0000x reference)
//
#include <hip/hip_runtime.h>
#include <cstdint>

#define DD     1024
#define NINNER 4096
#define NTOK   32768   // B*T = 8*4096
#define MROWS  8192    // tokens per expert

typedef unsigned short u16;
typedef __bf16 bf16x8 __attribute__((ext_vector_type(8)));
typedef float  f32x4  __attribute__((ext_vector_type(4)));

// fp32 -> bf16 round-to-nearest-even
__device__ __forceinline__ u16 f2bf(float f) {
    union { float f; uint32_t u; } a; a.f = f;
    uint32_t r = a.u + 0x7fffu + ((a.u >> 16) & 1u);
    return (u16)(r >> 16);
}

// async global->LDS, 16B per lane; LDS dest = wave-uniform base + lane*16
__device__ __forceinline__ void async16(const void* g, void* l) {
    __builtin_amdgcn_global_load_lds(
        (const __attribute__((address_space(1))) void*)g,
        (__attribute__((address_space(3))) void*)l,
        16, 0, 0);
}

// ---------------- weight cast: fp32 -> bf16 ----------------
__global__ __launch_bounds__(256) void cast_w(
    const float* __restrict__ w1, const float* __restrict__ w2,
    u16* __restrict__ w1b, u16* __restrict__ w2b)
{
    int idx = blockIdx.x * 256 + threadIdx.x;     // float4 index
    const int n1 = (NINNER * DD) / 4;             // 1M float4 in l1_w
    float4 v; ushort4 o;
    if (idx < n1) {
        v = ((const float4*)w1)[idx];
        o.x = f2bf(v.x); o.y = f2bf(v.y); o.z = f2bf(v.z); o.w = f2bf(v.w);
        ((ushort4*)w1b)[idx] = o;
    } else {
        int j = idx - n1;
        v = ((const float4*)w2)[j];
        o.x = f2bf(v.x); o.y = f2bf(v.y); o.z = f2bf(v.z); o.w = f2bf(v.w);
        ((ushort4*)w2b)[j] = o;
    }
}

// ---------------- LayerNorm (fp32) -> bf16 h, plus pad-region copy ----------------
__global__ __launch_bounds__(256) void ln_kernel(
    const float* __restrict__ x, const float* __restrict__ nw,
    const float* __restrict__ nb, u16* __restrict__ h,
    float* __restrict__ out)
{
    const int row = blockIdx.x;          // 0..32767 global token
    const int tid = threadIdx.x;
    const float4 v = ((const float4*)(x + (size_t)row * DD))[tid];
    float s  = v.x + v.y + v.z + v.w;
    float s2 = v.x*v.x + v.y*v.y + v.z*v.z + v.w*v.w;
#pragma unroll
    for (int o = 32; o > 0; o >>= 1) {
        s  += __shfl_down(s,  o, 64);
        s2 += __shfl_down(s2, o, 64);
    }
    __shared__ float as1[4], as2[4];
    if ((tid & 63) == 0) { as1[tid >> 6] = s; as2[tid >> 6] = s2; }
    __syncthreads();
    const float S  = as1[0] + as1[1] + as1[2] + as1[3];
    const float S2 = as2[0] + as2[1] + as2[2] + as2[3];
    const float mu  = S  * (1.0f / 1024.0f);
    const float var = S2 * (1.0f / 1024.0f) - mu * mu;
    const float rs  = rsqrtf(var + 1e-5f);
    const float4 w4 = ((const float4*)nw)[tid];
    const float4 b4 = ((const float4*)nb)[tid];
    ushort4 hv;
    hv.x = f2bf((v.x - mu) * rs * w4.x + b4.x);
    hv.y = f2bf((v.y - mu) * rs * w4.y + b4.y);
    hv.z = f2bf((v.z - mu) * rs * w4.z + b4.z);
    hv.w = f2bf((v.w - mu) * rs * w4.w + b4.w);
    ((ushort4*)(h + (size_t)row * DD))[tid] = hv;
    // pad region: out[:, :, m_e:] = x  (expert of this token: (row%4096)/1024)
    const int e = (row >> 10) & 3;
    const int m = DD >> e;
    if (tid * 4 >= m)
        ((float4*)(out + (size_t)row * DD))[tid] = v;
}

// ---------------- GEMM1: inner = gelu(h[:, :K] @ w1b[:, :K]^T + l1b), bf16 out ----------------
// A = h (token rows via expert mapping, ld=1024), B = w1b (4096 x 1024, ld=1024), C = inner (8192 x 4096)
__global__ __launch_bounds__(256) void gemm1(
    const u16* __restrict__ h, const u16* __restrict__ w1b,
    const float* __restrict__ l1b, u16* __restrict__ inner,
    int K, int e)
{
    __shared__ u16 lA[128 * 64];
    __shared__ u16 lB[128 * 64];
    const int tid  = threadIdx.x;
    const int lane = tid & 63;
    const int w    = tid >> 6;
    const int wr   = w >> 1, wc = w & 1;
    const int bm = blockIdx.y, bn = blockIdx.x;

    f32x4 acc[4][4] = {};

    // staging geometry (per thread, per i): chunk c covers 8 rows (8*128B = 1KB = 64 lanes * 16B)
    const int srow = (lane >> 3);        // row within chunk
    const int soff = (lane & 7) * 8;     // u16 offset within row (16B granules)

    for (int kt = 0; kt < K; kt += 64) {
#pragma unroll
        for (int i = 0; i < 4; ++i) {
            const int c   = w * 4 + i;
            const int row = c * 8 + srow;
            const int rl  = bm * 128 + row;
            const int g   = ((rl >> 10) << 12) + (e << 10) + (rl & 1023);
            async16(h + (size_t)g * DD + kt + soff, &lA[c * 512]);
        }
#pragma unroll
        for (int i = 0; i < 4; ++i) {
            const int c   = w * 4 + i;
            const int row = c * 8 + srow;
            async16(w1b + (size_t)(bn * 128 + row) * DD + kt + soff, &lB[c * 512]);
        }
        __syncthreads();
#pragma unroll
        for (int kk = 0; kk < 2; ++kk) {
            const int ko = kk * 32 + (lane >> 4) * 8;
            bf16x8 af[4], bq[4];
#pragma unroll
            for (int i = 0; i < 4; ++i)
                af[i] = *(const bf16x8*)&lA[(wr * 64 + i * 16 + (lane & 15)) * 64 + ko];
#pragma unroll
            for (int i = 0; i < 4; ++i)
                bq[i] = *(const bf16x8*)&lB[(wc * 64 + i * 16 + (lane & 15)) * 64 + ko];
#pragma unroll
            for (int mi = 0; mi < 4; ++mi)
#pragma unroll
                for (int ni = 0; ni < 4; ++ni)
                    acc[mi][ni] = __builtin_amdgcn_mfma_f32_16x16x32_bf16(
                        af[mi], bq[ni], acc[mi][ni], 0, 0, 0);
        }
        __syncthreads();
    }

    // epilogue: bias + exact GELU -> bf16
    const int cbase = bn * 128 + wc * 64 + (lane & 15);
    const int rbase = bm * 128 + wr * 64 + (lane >> 4) * 4;
#pragma unroll
    for (int ni = 0; ni < 4; ++ni) {
        const int col = cbase + ni * 16;
        const float bias = l1b[col];
#pragma unroll
        for (int mi = 0; mi < 4; ++mi) {
            const int r0 = rbase + mi * 16;
#pragma unroll
            for (int r = 0; r < 4; ++r) {
                const float vv = acc[mi][ni][r] + bias;
                const float gg = 0.5f * vv * (1.0f + erff(vv * 0.7071067811865476f));
                inner[(size_t)(r0 + r) * NINNER + col] = f2bf(gg);
            }
        }
    }
}

// ---------------- GEMM2: out = x + scale*(inner @ w2b[:N,:]^T + l2b) ----------------
// A = inner (8192 x 4096), B = w2b (1024 x 4096, use first N rows), K = 4096
__global__ __launch_bounds__(256) void gemm2(
    const u16* __restrict__ inner, const u16* __restrict__ w2b,
    const float* __restrict__ l2b, const float* __restrict__ x,
    const float* __restrict__ rp, const float* __restrict__ alphap,
    float* __restrict__ out, int e)
{
    __shared__ u16 lA[128 * 64];
    __shared__ u16 lB[128 * 64];
    const int tid  = threadIdx.x;
    const int lane = tid & 63;
    const int w    = tid >> 6;
    const int wr   = w >> 1, wc = w & 1;
    const int bm = blockIdx.y, bn = blockIdx.x;

    f32x4 acc[4][4] = {};
    const int srow = (lane >> 3);
    const int soff = (lane & 7) * 8;

    for (int kt = 0; kt < 4096; kt += 64) {
#pragma unroll
        for (int i = 0; i < 4; ++i) {
            const int c   = w * 4 + i;
            const int row = c * 8 + srow;
            async16(inner + (size_t)(bm * 128 + row) * NINNER + kt + soff, &lA[c * 512]);
        }
#pragma unroll
        for (int i = 0; i < 4; ++i) {
            const int c   = w * 4 + i;
            const int row = c * 8 + srow;
            async16(w2b + (size_t)(bn * 128 + row) * NINNER + kt + soff, &lB[c * 512]);
        }
        __syncthreads();
#pragma unroll
        for (int kk = 0; kk < 2; ++kk) {
            const int ko = kk * 32 + (lane >> 4) * 8;
            bf16x8 af[4], bq[4];
#pragma unroll
            for (int i = 0; i < 4; ++i)
                af[i] = *(const bf16x8*)&lA[(wr * 64 + i * 16 + (lane & 15)) * 64 + ko];
#pragma unroll
            for (int i = 0; i < 4; ++i)
                bq[i] = *(const bf16x8*)&lB[(wc * 64 + i * 16 + (lane & 15)) * 64 + ko];
#pragma unroll
            for (int mi = 0; mi < 4; ++mi)
#pragma unroll
                for (int ni = 0; ni < 4; ++ni)
                    acc[mi][ni] = __builtin_amdgcn_mfma_f32_16x16x32_bf16(
                        af[mi], bq[ni], acc[mi][ni], 0, 0, 0);
        }
        __syncthreads();
    }

    const float alpha = alphap[0];
    const int cbase = bn * 128 + wc * 64 + (lane & 15);
    const int rbase = bm * 128 + wr * 64 + (lane >> 4) * 4;
#pragma unroll
    for (int mi = 0; mi < 4; ++mi) {
#pragma unroll
        for (int r = 0; r < 4; ++r) {
            const int rl = rbase + mi * 16 + r;
            const int g  = ((rl >> 10) << 12) + (e << 10) + (rl & 1023);
            const float sc = alpha * rp[(size_t)g * 4 + e] + 1.0f;
#pragma unroll
            for (int ni = 0; ni < 4; ++ni) {
                const int col = cbase + ni * 16;
                const float v = acc[mi][ni][r] + l2b[col];
                out[(size_t)g * DD + col] = x[(size_t)g * DD + col] + sc * v;
            }
        }
    }
}

extern "C" void kernel_launch(void* const* d_in, const int* in_sizes, int n_in,
                              void* d_out, int out_size, void* d_ws, size_t ws_size,
                              hipStream_t stream) {
    const float* x     = (const float*)d_in[0];
    const float* rp    = (const float*)d_in[1];
    const float* alpha = (const float*)d_in[2];
    const float* nw    = (const float*)d_in[3];
    const float* nb    = (const float*)d_in[4];
    const float* l1w   = (const float*)d_in[5];
    const float* l1b   = (const float*)d_in[6];
    const float* l2w   = (const float*)d_in[7];
    const float* l2b   = (const float*)d_in[8];
    float* out = (float*)d_out;

    // workspace layout: h (64MB) | inner (64MB) | w1b (8MB) | w2b (8MB)
    char* ws = (char*)d_ws;
    if (ws_size < ((size_t)144 << 20)) return;  // loud failure rather than corruption
    u16* h     = (u16*)(ws);
    u16* inner = (u16*)(ws + ((size_t)64 << 20));
    u16* w1b   = (u16*)(ws + ((size_t)128 << 20));
    u16* w2b   = (u16*)(ws + ((size_t)136 << 20));

    cast_w<<<8192, 256, 0, stream>>>(l1w, l2w, w1b, w2b);
    ln_kernel<<<NTOK, 256, 0, stream>>>(x, nw, nb, h, out);
    for (int e = 0; e < 4; ++e) {
        const int m = DD >> e;
        gemm1<<<dim3(NINNER / 128, MROWS / 128), 256, 0, stream>>>(h, w1b, l1b, inner, m, e);
        gemm2<<<dim3(m / 128, MROWS / 128), 256, 0, stream>>>(inner, w2b, l2b, x, rp, alpha, out, e);
    }
}

// Round 2
// 870.095 us; speedup vs baseline: 1.1136x; 1.1136x over previous
//
#include <hip/hip_runtime.h>
#include <cstdint>

#define DD     1024
#define NINNER 4096
#define NTOK   32768   // B*T = 8*4096
#define MROWS  8192    // tokens per expert

typedef unsigned short u16;
typedef __bf16 bf16x8 __attribute__((ext_vector_type(8)));
typedef float  f32x4  __attribute__((ext_vector_type(4)));

// fp32 -> bf16 round-to-nearest-even
__device__ __forceinline__ u16 f2bf(float f) {
    union { float f; uint32_t u; } a; a.f = f;
    uint32_t r = a.u + 0x7fffu + ((a.u >> 16) & 1u);
    return (u16)(r >> 16);
}

// async global->LDS, 16B per lane; LDS dest = wave-uniform base + lane*16
__device__ __forceinline__ void async16(const void* g, void* l) {
    __builtin_amdgcn_global_load_lds(
        (const __attribute__((address_space(1))) void*)g,
        (__attribute__((address_space(3))) void*)l,
        16, 0, 0);
}

// ---------------- weight cast: fp32 -> bf16 ----------------
__global__ __launch_bounds__(256) void cast_w(
    const float* __restrict__ w1, const float* __restrict__ w2,
    u16* __restrict__ w1b, u16* __restrict__ w2b)
{
    int idx = blockIdx.x * 256 + threadIdx.x;     // float4 index
    const int n1 = (NINNER * DD) / 4;             // 1M float4 in l1_w
    float4 v; ushort4 o;
    if (idx < n1) {
        v = ((const float4*)w1)[idx];
        o.x = f2bf(v.x); o.y = f2bf(v.y); o.z = f2bf(v.z); o.w = f2bf(v.w);
        ((ushort4*)w1b)[idx] = o;
    } else {
        int j = idx - n1;
        v = ((const float4*)w2)[j];
        o.x = f2bf(v.x); o.y = f2bf(v.y); o.z = f2bf(v.z); o.w = f2bf(v.w);
        ((ushort4*)w2b)[j] = o;
    }
}

// ---------------- LayerNorm (fp32) -> bf16 h, plus pad-region copy ----------------
__global__ __launch_bounds__(256) void ln_kernel(
    const float* __restrict__ x, const float* __restrict__ nw,
    const float* __restrict__ nb, u16* __restrict__ h,
    float* __restrict__ out)
{
    const int row = blockIdx.x;          // 0..32767 global token
    const int tid = threadIdx.x;
    const float4 v = ((const float4*)(x + (size_t)row * DD))[tid];
    float s  = v.x + v.y + v.z + v.w;
    float s2 = v.x*v.x + v.y*v.y + v.z*v.z + v.w*v.w;
#pragma unroll
    for (int o = 32; o > 0; o >>= 1) {
        s  += __shfl_down(s,  o, 64);
        s2 += __shfl_down(s2, o, 64);
    }
    __shared__ float as1[4], as2[4];
    if ((tid & 63) == 0) { as1[tid >> 6] = s; as2[tid >> 6] = s2; }
    __syncthreads();
    const float S  = as1[0] + as1[1] + as1[2] + as1[3];
    const float S2 = as2[0] + as2[1] + as2[2] + as2[3];
    const float mu  = S  * (1.0f / 1024.0f);
    const float var = S2 * (1.0f / 1024.0f) - mu * mu;
    const float rs  = rsqrtf(var + 1e-5f);
    const float4 w4 = ((const float4*)nw)[tid];
    const float4 b4 = ((const float4*)nb)[tid];
    ushort4 hv;
    hv.x = f2bf((v.x - mu) * rs * w4.x + b4.x);
    hv.y = f2bf((v.y - mu) * rs * w4.y + b4.y);
    hv.z = f2bf((v.z - mu) * rs * w4.z + b4.z);
    hv.w = f2bf((v.w - mu) * rs * w4.w + b4.w);
    ((ushort4*)(h + (size_t)row * DD))[tid] = hv;
    // pad region: out[:, :, m_e:] = x  (expert of this token: (row%4096)/1024)
    const int e = (row >> 10) & 3;
    const int m = DD >> e;
    if (tid * 4 >= m)
        ((float4*)(out + (size_t)row * DD))[tid] = v;
}

// XOR-swizzled LDS tile: slot (row, granule g) holds global granule g ^ (row&7).
// Staging: lane loads source granule (lane&7) ^ (lane>>3)  [dest fixed at lane*16].
// Reading: global granule gg at row r lives at LDS granule gg ^ (r&7); since
// fragment rows satisfy r&7 == lane&7, the per-lane swizzled granule is
// ((kk*4 + (lane>>4)) ^ (lane&7)) — invariant across the 4 fragment reads.

// ---------------- GEMM1: inner = gelu(h[:, :K] @ w1b[:, :K]^T + l1b), bf16 out ----------------
__global__ __launch_bounds__(256) void gemm1(
    const u16* __restrict__ h, const u16* __restrict__ w1b,
    const float* __restrict__ l1b, u16* __restrict__ inner,
    int K, int e)
{
    __shared__ u16 lA[128 * 64];
    __shared__ u16 lB[128 * 64];
    const int tid  = threadIdx.x;
    const int lane = tid & 63;
    const int w    = tid >> 6;
    const int wr   = w >> 1, wc = w & 1;
    const int bm = blockIdx.y, bn = blockIdx.x;

    f32x4 acc[4][4] = {};

    // staging geometry: chunk c covers 8 rows (8*128B = 1KB = 64 lanes * 16B)
    const int srow = (lane >> 3);                       // row within chunk
    const int soff = ((lane & 7) ^ srow) * 8;           // swizzled u16 offset in row

    for (int kt = 0; kt < K; kt += 64) {
#pragma unroll
        for (int i = 0; i < 4; ++i) {
            const int c   = w * 4 + i;
            const int row = c * 8 + srow;
            const int rl  = bm * 128 + row;
            const int g   = ((rl >> 10) << 12) + (e << 10) + (rl & 1023);
            async16(h + (size_t)g * DD + kt + soff, &lA[c * 512]);
        }
#pragma unroll
        for (int i = 0; i < 4; ++i) {
            const int c   = w * 4 + i;
            const int row = c * 8 + srow;
            async16(w1b + (size_t)(bn * 128 + row) * DD + kt + soff, &lB[c * 512]);
        }
        __syncthreads();
#pragma unroll
        for (int kk = 0; kk < 2; ++kk) {
            const int sg = ((kk * 4 + (lane >> 4)) ^ (lane & 7)) * 8; // swizzled granule offset (u16)
            bf16x8 af[4], bq[4];
#pragma unroll
            for (int i = 0; i < 4; ++i)
                af[i] = *(const bf16x8*)&lA[(wr * 64 + i * 16 + (lane & 15)) * 64 + sg];
#pragma unroll
            for (int i = 0; i < 4; ++i)
                bq[i] = *(const bf16x8*)&lB[(wc * 64 + i * 16 + (lane & 15)) * 64 + sg];
#pragma unroll
            for (int mi = 0; mi < 4; ++mi)
#pragma unroll
                for (int ni = 0; ni < 4; ++ni)
                    acc[mi][ni] = __builtin_amdgcn_mfma_f32_16x16x32_bf16(
                        af[mi], bq[ni], acc[mi][ni], 0, 0, 0);
        }
        __syncthreads();
    }

    // epilogue: bias + exact GELU -> bf16
    const int cbase = bn * 128 + wc * 64 + (lane & 15);
    const int rbase = bm * 128 + wr * 64 + (lane >> 4) * 4;
#pragma unroll
    for (int ni = 0; ni < 4; ++ni) {
        const int col = cbase + ni * 16;
        const float bias = l1b[col];
#pragma unroll
        for (int mi = 0; mi < 4; ++mi) {
            const int r0 = rbase + mi * 16;
#pragma unroll
            for (int r = 0; r < 4; ++r) {
                const float vv = acc[mi][ni][r] + bias;
                const float gg = 0.5f * vv * (1.0f + erff(vv * 0.7071067811865476f));
                inner[(size_t)(r0 + r) * NINNER + col] = f2bf(gg);
            }
        }
    }
}

// ---------------- GEMM2: out = x + scale*(inner @ w2b[:N,:]^T + l2b) ----------------
__global__ __launch_bounds__(256) void gemm2(
    const u16* __restrict__ inner, const u16* __restrict__ w2b,
    const float* __restrict__ l2b, const float* __restrict__ x,
    const float* __restrict__ rp, const float* __restrict__ alphap,
    float* __restrict__ out, int e)
{
    __shared__ u16 lA[128 * 64];
    __shared__ u16 lB[128 * 64];
    const int tid  = threadIdx.x;
    const int lane = tid & 63;
    const int w    = tid >> 6;
    const int wr   = w >> 1, wc = w & 1;
    const int bm = blockIdx.y, bn = blockIdx.x;

    f32x4 acc[4][4] = {};
    const int srow = (lane >> 3);
    const int soff = ((lane & 7) ^ srow) * 8;

    for (int kt = 0; kt < 4096; kt += 64) {
#pragma unroll
        for (int i = 0; i < 4; ++i) {
            const int c   = w * 4 + i;
            const int row = c * 8 + srow;
            async16(inner + (size_t)(bm * 128 + row) * NINNER + kt + soff, &lA[c * 512]);
        }
#pragma unroll
        for (int i = 0; i < 4; ++i) {
            const int c   = w * 4 + i;
            const int row = c * 8 + srow;
            async16(w2b + (size_t)(bn * 128 + row) * NINNER + kt + soff, &lB[c * 512]);
        }
        __syncthreads();
#pragma unroll
        for (int kk = 0; kk < 2; ++kk) {
            const int sg = ((kk * 4 + (lane >> 4)) ^ (lane & 7)) * 8;
            bf16x8 af[4], bq[4];
#pragma unroll
            for (int i = 0; i < 4; ++i)
                af[i] = *(const bf16x8*)&lA[(wr * 64 + i * 16 + (lane & 15)) * 64 + sg];
#pragma unroll
            for (int i = 0; i < 4; ++i)
                bq[i] = *(const bf16x8*)&lB[(wc * 64 + i * 16 + (lane & 15)) * 64 + sg];
#pragma unroll
            for (int mi = 0; mi < 4; ++mi)
#pragma unroll
                for (int ni = 0; ni < 4; ++ni)
                    acc[mi][ni] = __builtin_amdgcn_mfma_f32_16x16x32_bf16(
                        af[mi], bq[ni], acc[mi][ni], 0, 0, 0);
        }
        __syncthreads();
    }

    const float alpha = alphap[0];
    const int cbase = bn * 128 + wc * 64 + (lane & 15);
    const int rbase = bm * 128 + wr * 64 + (lane >> 4) * 4;
#pragma unroll
    for (int mi = 0; mi < 4; ++mi) {
#pragma unroll
        for (int r = 0; r < 4; ++r) {
            const int rl = rbase + mi * 16 + r;
            const int g  = ((rl >> 10) << 12) + (e << 10) + (rl & 1023);
            const float sc = alpha * rp[(size_t)g * 4 + e] + 1.0f;
#pragma unroll
            for (int ni = 0; ni < 4; ++ni) {
                const int col = cbase + ni * 16;
                const float v = acc[mi][ni][r] + l2b[col];
                out[(size_t)g * DD + col] = x[(size_t)g * DD + col] + sc * v;
            }
        }
    }
}

extern "C" void kernel_launch(void* const* d_in, const int* in_sizes, int n_in,
                              void* d_out, int out_size, void* d_ws, size_t ws_size,
                              hipStream_t stream) {
    const float* x     = (const float*)d_in[0];
    const float* rp    = (const float*)d_in[1];
    const float* alpha = (const float*)d_in[2];
    const float* nw    = (const float*)d_in[3];
    const float* nb    = (const float*)d_in[4];
    const float* l1w   = (const float*)d_in[5];
    const float* l1b   = (const float*)d_in[6];
    const float* l2w   = (const float*)d_in[7];
    const float* l2b   = (const float*)d_in[8];
    float* out = (float*)d_out;

    // workspace layout: h (64MB) | inner (64MB) | w1b (8MB) | w2b (8MB)
    char* ws = (char*)d_ws;
    if (ws_size < ((size_t)144 << 20)) return;  // loud failure rather than corruption
    u16* h     = (u16*)(ws);
    u16* inner = (u16*)(ws + ((size_t)64 << 20));
    u16* w1b   = (u16*)(ws + ((size_t)128 << 20));
    u16* w2b   = (u16*)(ws + ((size_t)136 << 20));

    cast_w<<<8192, 256, 0, stream>>>(l1w, l2w, w1b, w2b);
    ln_kernel<<<NTOK, 256, 0, stream>>>(x, nw, nb, h, out);
    for (int e = 0; e < 4; ++e) {
        const int m = DD >> e;
        gemm1<<<dim3(NINNER / 128, MROWS / 128), 256, 0, stream>>>(h, w1b, l1b, inner, m, e);
        gemm2<<<dim3(m / 128, MROWS / 128), 256, 0, stream>>>(inner, w2b, l2b, x, rp, alpha, out, e);
    }
}

// Round 3
// 864.390 us; speedup vs baseline: 1.1209x; 1.0066x over previous
//
#include <hip/hip_runtime.h>
#include <cstdint>

#define DD     1024
#define NINNER 4096
#define NTOK   32768   // B*T = 8*4096
#define MROWS  8192    // tokens per expert

typedef unsigned short u16;
typedef __bf16 bf16x8 __attribute__((ext_vector_type(8)));
typedef float  f32x4  __attribute__((ext_vector_type(4)));

// fp32 -> bf16 round-to-nearest-even
__device__ __forceinline__ u16 f2bf(float f) {
    union { float f; uint32_t u; } a; a.f = f;
    uint32_t r = a.u + 0x7fffu + ((a.u >> 16) & 1u);
    return (u16)(r >> 16);
}

// async global->LDS, 16B per lane; LDS dest = wave-uniform base + lane*16
__device__ __forceinline__ void async16(const void* g, void* l) {
    __builtin_amdgcn_global_load_lds(
        (const __attribute__((address_space(1))) void*)g,
        (__attribute__((address_space(3))) void*)l,
        16, 0, 0);
}

// ---------------- weight cast: fp32 -> bf16 ----------------
__global__ __launch_bounds__(256) void cast_w(
    const float* __restrict__ w1, const float* __restrict__ w2,
    u16* __restrict__ w1b, u16* __restrict__ w2b)
{
    int idx = blockIdx.x * 256 + threadIdx.x;     // float4 index
    const int n1 = (NINNER * DD) / 4;             // 1M float4 in l1_w
    float4 v; ushort4 o;
    if (idx < n1) {
        v = ((const float4*)w1)[idx];
        o.x = f2bf(v.x); o.y = f2bf(v.y); o.z = f2bf(v.z); o.w = f2bf(v.w);
        ((ushort4*)w1b)[idx] = o;
    } else {
        int j = idx - n1;
        v = ((const float4*)w2)[j];
        o.x = f2bf(v.x); o.y = f2bf(v.y); o.z = f2bf(v.z); o.w = f2bf(v.w);
        ((ushort4*)w2b)[j] = o;
    }
}

// ---------------- LayerNorm -> bf16 h, plus FULL out init ----------------
// out[:, :m] = x + sc*l2b   (gemm2 atomically adds sc*acc on top)
// out[:, m:] = x            (pad region)
__global__ __launch_bounds__(256) void ln_kernel(
    const float* __restrict__ x, const float* __restrict__ nw,
    const float* __restrict__ nb, const float* __restrict__ l2b,
    const float* __restrict__ rp, const float* __restrict__ alphap,
    u16* __restrict__ h, float* __restrict__ out)
{
    const int row = blockIdx.x;          // 0..32767 global token
    const int tid = threadIdx.x;
    const float4 v = ((const float4*)(x + (size_t)row * DD))[tid];
    float s  = v.x + v.y + v.z + v.w;
    float s2 = v.x*v.x + v.y*v.y + v.z*v.z + v.w*v.w;
#pragma unroll
    for (int o = 32; o > 0; o >>= 1) {
        s  += __shfl_down(s,  o, 64);
        s2 += __shfl_down(s2, o, 64);
    }
    __shared__ float as1[4], as2[4];
    if ((tid & 63) == 0) { as1[tid >> 6] = s; as2[tid >> 6] = s2; }
    __syncthreads();
    const float S  = as1[0] + as1[1] + as1[2] + as1[3];
    const float S2 = as2[0] + as2[1] + as2[2] + as2[3];
    const float mu  = S  * (1.0f / 1024.0f);
    const float var = S2 * (1.0f / 1024.0f) - mu * mu;
    const float rs  = rsqrtf(var + 1e-5f);
    const float4 w4 = ((const float4*)nw)[tid];
    const float4 b4 = ((const float4*)nb)[tid];
    ushort4 hv;
    hv.x = f2bf((v.x - mu) * rs * w4.x + b4.x);
    hv.y = f2bf((v.y - mu) * rs * w4.y + b4.y);
    hv.z = f2bf((v.z - mu) * rs * w4.z + b4.z);
    hv.w = f2bf((v.w - mu) * rs * w4.w + b4.w);
    ((ushort4*)(h + (size_t)row * DD))[tid] = hv;

    const int e = (row >> 10) & 3;       // expert of this token: (row%4096)/1024
    const int m = DD >> e;
    float4 o4;
    if (tid * 4 < m) {                   // m % 128 == 0 -> uniform per float4
        const float sc = alphap[0] * rp[(size_t)row * 4 + e] + 1.0f;
        const float4 lb = ((const float4*)l2b)[tid];
        o4.x = v.x + sc * lb.x; o4.y = v.y + sc * lb.y;
        o4.z = v.z + sc * lb.z; o4.w = v.w + sc * lb.w;
    } else {
        o4 = v;
    }
    ((float4*)(out + (size_t)row * DD))[tid] = o4;
}

// XOR-swizzled LDS tile: slot (row, granule g) holds global granule g ^ (row&7).
// Staging: lane loads source granule (lane&7) ^ (lane>>3)  [dest fixed at lane*16].
// Reading: fragment rows satisfy r&7 == lane&7 -> swizzled granule offset is
// ((kk*4 + (lane>>4)) ^ (lane&7)), invariant across the 4 fragment reads.

// ---------------- GEMM1: inner = gelu(h[:, :K] @ w1b[:, :K]^T + l1b), bf16 out ----------------
__global__ __launch_bounds__(256) void gemm1(
    const u16* __restrict__ h, const u16* __restrict__ w1b,
    const float* __restrict__ l1b, u16* __restrict__ inner,
    int K, int e)
{
    __shared__ u16 lA[128 * 64];
    __shared__ u16 lB[128 * 64];
    const int tid  = threadIdx.x;
    const int lane = tid & 63;
    const int w    = tid >> 6;
    const int wr   = w >> 1, wc = w & 1;
    const int bm = blockIdx.y, bn = blockIdx.x;

    f32x4 acc[4][4] = {};

    const int srow = (lane >> 3);                       // row within 8-row chunk
    const int soff = ((lane & 7) ^ srow) * 8;           // swizzled u16 offset in row

    for (int kt = 0; kt < K; kt += 64) {
#pragma unroll
        for (int i = 0; i < 4; ++i) {
            const int c   = w * 4 + i;
            const int row = c * 8 + srow;
            const int rl  = bm * 128 + row;
            const int g   = ((rl >> 10) << 12) + (e << 10) + (rl & 1023);
            async16(h + (size_t)g * DD + kt + soff, &lA[c * 512]);
        }
#pragma unroll
        for (int i = 0; i < 4; ++i) {
            const int c   = w * 4 + i;
            const int row = c * 8 + srow;
            async16(w1b + (size_t)(bn * 128 + row) * DD + kt + soff, &lB[c * 512]);
        }
        __syncthreads();
#pragma unroll
        for (int kk = 0; kk < 2; ++kk) {
            const int sg = ((kk * 4 + (lane >> 4)) ^ (lane & 7)) * 8;
            bf16x8 af[4], bq[4];
#pragma unroll
            for (int i = 0; i < 4; ++i)
                af[i] = *(const bf16x8*)&lA[(wr * 64 + i * 16 + (lane & 15)) * 64 + sg];
#pragma unroll
            for (int i = 0; i < 4; ++i)
                bq[i] = *(const bf16x8*)&lB[(wc * 64 + i * 16 + (lane & 15)) * 64 + sg];
#pragma unroll
            for (int mi = 0; mi < 4; ++mi)
#pragma unroll
                for (int ni = 0; ni < 4; ++ni)
                    acc[mi][ni] = __builtin_amdgcn_mfma_f32_16x16x32_bf16(
                        af[mi], bq[ni], acc[mi][ni], 0, 0, 0);
        }
        __syncthreads();
    }

    // epilogue: bias + exact GELU -> bf16
    const int cbase = bn * 128 + wc * 64 + (lane & 15);
    const int rbase = bm * 128 + wr * 64 + (lane >> 4) * 4;
#pragma unroll
    for (int ni = 0; ni < 4; ++ni) {
        const int col = cbase + ni * 16;
        const float bias = l1b[col];
#pragma unroll
        for (int mi = 0; mi < 4; ++mi) {
            const int r0 = rbase + mi * 16;
#pragma unroll
            for (int r = 0; r < 4; ++r) {
                const float vv = acc[mi][ni][r] + bias;
                const float gg = 0.5f * vv * (1.0f + erff(vv * 0.7071067811865476f));
                inner[(size_t)(r0 + r) * NINNER + col] = f2bf(gg);
            }
        }
    }
}

// ---------------- GEMM2 (split-K, XCD-grouped): out += sc * (inner @ w2b[:N,:]^T) ----------------
// Block decode: id&7 = XCD slot; all chunks of one bm share it -> A-tile stays in one L2.
// chunk in [0, CPB): bn = chunk & (Bn-1), s = chunk >> lgBn; K-range [s*Kc, (s+1)*Kc).
__global__ __launch_bounds__(256) void gemm2(
    const u16* __restrict__ inner, const u16* __restrict__ w2b,
    const float* __restrict__ rp, const float* __restrict__ alphap,
    float* __restrict__ out, int e, int lgBn, int lgCPB)
{
    __shared__ u16 lA[128 * 64];
    __shared__ u16 lB[128 * 64];
    const int tid  = threadIdx.x;
    const int lane = tid & 63;
    const int w    = tid >> 6;
    const int wr   = w >> 1, wc = w & 1;

    const int id    = blockIdx.x;
    const int xcd   = id & 7;
    const int j     = id >> 3;
    const int bm    = ((j >> lgCPB) << 3) | xcd;
    const int chunk = j & ((1 << lgCPB) - 1);
    const int bn    = chunk & ((1 << lgBn) - 1);
    const int s     = chunk >> lgBn;
    const int Kc    = NINNER >> (lgCPB - lgBn);     // 4096 / S
    const int k0    = s * Kc;

    f32x4 acc[4][4] = {};
    const int srow = (lane >> 3);
    const int soff = ((lane & 7) ^ srow) * 8;

    for (int kt = k0; kt < k0 + Kc; kt += 64) {
#pragma unroll
        for (int i = 0; i < 4; ++i) {
            const int c   = w * 4 + i;
            const int row = c * 8 + srow;
            async16(inner + (size_t)(bm * 128 + row) * NINNER + kt + soff, &lA[c * 512]);
        }
#pragma unroll
        for (int i = 0; i < 4; ++i) {
            const int c   = w * 4 + i;
            const int row = c * 8 + srow;
            async16(w2b + (size_t)(bn * 128 + row) * NINNER + kt + soff, &lB[c * 512]);
        }
        __syncthreads();
#pragma unroll
        for (int kk = 0; kk < 2; ++kk) {
            const int sg = ((kk * 4 + (lane >> 4)) ^ (lane & 7)) * 8;
            bf16x8 af[4], bq[4];
#pragma unroll
            for (int i = 0; i < 4; ++i)
                af[i] = *(const bf16x8*)&lA[(wr * 64 + i * 16 + (lane & 15)) * 64 + sg];
#pragma unroll
            for (int i = 0; i < 4; ++i)
                bq[i] = *(const bf16x8*)&lB[(wc * 64 + i * 16 + (lane & 15)) * 64 + sg];
#pragma unroll
            for (int mi = 0; mi < 4; ++mi)
#pragma unroll
                for (int ni = 0; ni < 4; ++ni)
                    acc[mi][ni] = __builtin_amdgcn_mfma_f32_16x16x32_bf16(
                        af[mi], bq[ni], acc[mi][ni], 0, 0, 0);
        }
        __syncthreads();
    }

    const float alpha = alphap[0];
    const int cbase = bn * 128 + wc * 64 + (lane & 15);
    const int rbase = bm * 128 + wr * 64 + (lane >> 4) * 4;
#pragma unroll
    for (int mi = 0; mi < 4; ++mi) {
#pragma unroll
        for (int r = 0; r < 4; ++r) {
            const int rl = rbase + mi * 16 + r;
            const int g  = ((rl >> 10) << 12) + (e << 10) + (rl & 1023);
            const float sc = alpha * rp[(size_t)g * 4 + e] + 1.0f;
#pragma unroll
            for (int ni = 0; ni < 4; ++ni) {
                const int col = cbase + ni * 16;
                unsafeAtomicAdd(out + (size_t)g * DD + col, sc * acc[mi][ni][r]);
            }
        }
    }
}

extern "C" void kernel_launch(void* const* d_in, const int* in_sizes, int n_in,
                              void* d_out, int out_size, void* d_ws, size_t ws_size,
                              hipStream_t stream) {
    const float* x     = (const float*)d_in[0];
    const float* rp    = (const float*)d_in[1];
    const float* alpha = (const float*)d_in[2];
    const float* nw    = (const float*)d_in[3];
    const float* nb    = (const float*)d_in[4];
    const float* l1w   = (const float*)d_in[5];
    const float* l1b   = (const float*)d_in[6];
    const float* l2w   = (const float*)d_in[7];
    const float* l2b   = (const float*)d_in[8];
    float* out = (float*)d_out;

    // workspace layout: h (64MB) | inner (64MB) | w1b (8MB) | w2b (8MB)
    char* ws = (char*)d_ws;
    if (ws_size < ((size_t)144 << 20)) return;  // loud failure rather than corruption
    u16* h     = (u16*)(ws);
    u16* inner = (u16*)(ws + ((size_t)64 << 20));
    u16* w1b   = (u16*)(ws + ((size_t)128 << 20));
    u16* w2b   = (u16*)(ws + ((size_t)136 << 20));

    cast_w<<<8192, 256, 0, stream>>>(l1w, l2w, w1b, w2b);
    ln_kernel<<<NTOK, 256, 0, stream>>>(x, nw, nb, l2b, rp, alpha, h, out);
    // split-K config per expert: Bn = m/128, CPB = Bn*S (chunks per bm-row)
    static const int lgBn_t[4]  = {3, 2, 1, 0};
    static const int lgCPB_t[4] = {4, 4, 4, 3};   // S = 2,4,8,8 -> 1024,1024,1024,512 blocks
    for (int e = 0; e < 4; ++e) {
        const int m = DD >> e;
        gemm1<<<dim3(NINNER / 128, MROWS / 128), 256, 0, stream>>>(h, w1b, l1b, inner, m, e);
        gemm2<<<64 << lgCPB_t[e], 256, 0, stream>>>(inner, w2b, rp, alpha, out, e,
                                                    lgBn_t[e], lgCPB_t[e]);
    }
}